// Round 6
// baseline (147.621 us; speedup 1.0000x reference)
//
#include <hip/hip_runtime.h>
#include <math.h>

// SS2D: B=1, D=96, H=W=96, L=9216, K=4, N=16, R=6
constexpr int cD = 96, cL = 9216, cK = 4;
constexpr int NCH = 64, CLEN = 144;     // 64 chunks x 144 per sequence
constexpr float LOG2E = 1.44269504088896f;

// ws float offsets (~33 MB)
constexpr long OFF_XT    = 0;                       // [96][9216] transposed x
constexpr long OFF_DELTA = OFF_XT    + (long)cD*cL; // [K][96][9216]  (d-major)
constexpr long OFF_BS    = OFF_DELTA + 4L*cD*cL;    // [K][9216][16]
constexpr long OFF_CS    = OFF_BS    + 4L*cL*16;    // [K][9216][16]
constexpr long OFF_Y     = OFF_CS    + 4L*cL*16;    // [K][9216][96] (position-major)

// ---- kT: xT[d][w*96+h] = x[d][h*96+w] --------------------------------------
__global__ __launch_bounds__(256) void kT(const float* __restrict__ x,
                                          float* __restrict__ xT) {
    __shared__ float t[32][33];
    const int h0 = blockIdx.x * 32, w0 = blockIdx.y * 32, d = blockIdx.z;
    const float* xd = x + (long)d * cL;
    float* xtd = xT + (long)d * cL;
    for (int o = threadIdx.x; o < 1024; o += 256) {
        int i = o >> 5, j = o & 31;
        t[i][j] = xd[(h0 + i) * 96 + w0 + j];
    }
    __syncthreads();
    for (int o = threadIdx.x; o < 1024; o += 256) {
        int i = o >> 5, j = o & 31;
        xtd[(w0 + i) * 96 + h0 + j] = t[j][i];
    }
}

// ---- kA: G = W_k @ src_k; delta[k][d][p] (d-major), Bs/Cs[k][p][16] --------
__global__ __launch_bounds__(256) void kA(const float* __restrict__ x,
                                          const float* __restrict__ xT,
                                          const float* __restrict__ xpw,
                                          const float* __restrict__ dtw,
                                          const float* __restrict__ dtb,
                                          float* __restrict__ delta,
                                          float* __restrict__ Bs,
                                          float* __restrict__ Cs) {
    __shared__ float xs[96][64];
    __shared__ float xdbl[38][65];
    __shared__ float dtw_l[96 * 6];
    __shared__ float dtb_l[96];
    const int p0 = blockIdx.x * 64;
    const int k  = blockIdx.y;
    const int tid = threadIdx.x;
    const float* src = (k & 1) ? xT : x;

    for (int o = tid; o < 96 * 64; o += 256) {
        int dd = o >> 6, pp = o & 63;
        xs[dd][pp] = src[(long)dd * cL + p0 + pp];
    }
    for (int o = tid; o < 96 * 6; o += 256) dtw_l[o] = dtw[k * 96 * 6 + o];
    if (tid < 96) dtb_l[tid] = dtb[k * 96 + tid];
    __syncthreads();

    const int lane = tid & 63;
    const int c0 = __builtin_amdgcn_readfirstlane((tid >> 6) * 10);
    const float* wk = xpw + (long)k * 38 * 96;
    float acc[10];
    #pragma unroll
    for (int i = 0; i < 10; ++i) acc[i] = 0.f;
    #pragma unroll 4
    for (int dd = 0; dd < 96; ++dd) {
        float xv = xs[dd][lane];
        #pragma unroll
        for (int i = 0; i < 10; ++i) {
            int c = c0 + i; c = c > 37 ? 37 : c;
            acc[i] = fmaf(xv, wk[c * 96 + dd], acc[i]);
        }
    }
    #pragma unroll
    for (int i = 0; i < 10; ++i) {
        int c = c0 + i; c = c > 37 ? 37 : c;
        xdbl[c][lane] = acc[i];
    }
    __syncthreads();

    for (int o = tid; o < 64 * 16; o += 256) {
        int n = o & 15, pp = o >> 4;
        long idx = ((long)k * cL + p0 + pp) * 16 + n;
        Bs[idx] = xdbl[6 + n][pp];
        Cs[idx] = xdbl[22 + n][pp];
    }
    for (int o = tid; o < 96 * 64; o += 256) {
        int dd = o >> 6, pp = o & 63;
        float s = dtb_l[dd];
        #pragma unroll
        for (int r = 0; r < 6; ++r) s = fmaf(xdbl[r][pp], dtw_l[dd * 6 + r], s);
        float sp = fmaxf(s, 0.f) + __logf(1.f + __expf(-fabsf(s)));
        delta[((long)(k * 96 + dd)) * cL + p0 + pp] = sp;
    }
}

// ---- kS: fused scan. One block per (k,d); 1024 thr = 64 chunks x 16 n ------
template<int REV>
__device__ __forceinline__ void scan_body(const float* __restrict__ dRow,
                                          const float* __restrict__ xRow,
                                          const float* __restrict__ bPl,
                                          const float* __restrict__ cPl,
                                          float* __restrict__ yPl,
                                          float a2n, float Dv, int ch, int n,
                                          float (*lp)[16], float (*ls)[16]) {
    const int pb = REV ? (cL - 1 - ch * CLEN) : ch * CLEN;

    // pass 1: chunk summary
    float h = 0.f, sdl = 0.f;
    for (int g = 0; g < CLEN / 4; ++g) {
        const int p0 = REV ? pb - 4 * g : pb + 4 * g;
        const int plo = REV ? p0 - 3 : p0;
        float4 d4 = *(const float4*)(dRow + plo);
        float4 x4 = *(const float4*)(xRow + plo);
#define P1STEP(DL, XV, P) { float bv = bPl[(long)(P) * 16];                  \
        float e = exp2f((DL) * a2n); h = fmaf(e, h, (DL) * (XV) * bv);       \
        sdl += (DL); }
        if (REV) {
            P1STEP(d4.w, x4.w, p0)     P1STEP(d4.z, x4.z, p0 - 1)
            P1STEP(d4.y, x4.y, p0 - 2) P1STEP(d4.x, x4.x, p0 - 3)
        } else {
            P1STEP(d4.x, x4.x, p0)     P1STEP(d4.y, x4.y, p0 + 1)
            P1STEP(d4.z, x4.z, p0 + 2) P1STEP(d4.w, x4.w, p0 + 3)
        }
#undef P1STEP
    }
    lp[ch][n] = exp2f(a2n * sdl);
    ls[ch][n] = h;
    __syncthreads();

    // Kogge-Stone inclusive scan over 64 chunks (per n)
    #pragma unroll
    for (int off = 1; off < NCH; off <<= 1) {
        float pc = lp[ch][n], sc = ls[ch][n];
        float pn = pc, sn = sc;
        if (ch >= off) {
            float pq = lp[ch - off][n], sq = ls[ch - off][n];
            pn = pc * pq;
            sn = fmaf(pc, sq, sc);
        }
        __syncthreads();
        lp[ch][n] = pn; ls[ch][n] = sn;
        __syncthreads();
    }
    h = (ch == 0) ? 0.f : ls[ch - 1][n];

    // pass 2: replay with correct init, emit y
    for (int g = 0; g < CLEN / 4; ++g) {
        const int p0 = REV ? pb - 4 * g : pb + 4 * g;
        const int plo = REV ? p0 - 3 : p0;
        float4 d4 = *(const float4*)(dRow + plo);
        float4 x4 = *(const float4*)(xRow + plo);
#define P2STEP(DL, XV, P) { float bv = bPl[(long)(P) * 16];                  \
        float cv = cPl[(long)(P) * 16];                                      \
        float e = exp2f((DL) * a2n); h = fmaf(e, h, (DL) * (XV) * bv);       \
        float pv = h * cv;                                                   \
        pv += __shfl_xor(pv, 1, 16); pv += __shfl_xor(pv, 2, 16);            \
        pv += __shfl_xor(pv, 4, 16); pv += __shfl_xor(pv, 8, 16);            \
        if (n == 0) yPl[(long)(P) * 96] = fmaf(Dv, (XV), pv); }
        if (REV) {
            P2STEP(d4.w, x4.w, p0)     P2STEP(d4.z, x4.z, p0 - 1)
            P2STEP(d4.y, x4.y, p0 - 2) P2STEP(d4.x, x4.x, p0 - 3)
        } else {
            P2STEP(d4.x, x4.x, p0)     P2STEP(d4.y, x4.y, p0 + 1)
            P2STEP(d4.z, x4.z, p0 + 2) P2STEP(d4.w, x4.w, p0 + 3)
        }
#undef P2STEP
    }
}

__global__ __launch_bounds__(1024, 8) void kS(const float* __restrict__ x,
                                              const float* __restrict__ xT,
                                              const float* __restrict__ delta,
                                              const float* __restrict__ Bs,
                                              const float* __restrict__ Cs,
                                              const float* __restrict__ Alog,
                                              const float* __restrict__ Dsv,
                                              float* __restrict__ y) {
    __shared__ float lp[NCH][16];
    __shared__ float ls[NCH][16];
    const int tid = threadIdx.x;
    const int n = tid & 15, ch = tid >> 4;
    const int k = blockIdx.x / 96, d = blockIdx.x % 96;
    const float* srcx = (k & 1) ? xT : x;

    const float a2n = -LOG2E * exp2f(LOG2E * Alog[((long)(k * 96 + d)) * 16 + n]);
    const float Dv = Dsv[k * 96 + d];
    const float* dRow = delta + ((long)(k * 96 + d)) * cL;
    const float* xRow = srcx + (long)d * cL;
    const float* bPl = Bs + (long)k * cL * 16 + n;
    const float* cPl = Cs + (long)k * cL * 16 + n;
    float* yPl = y + (long)k * cL * 96 + d;

    if (k < 2) scan_body<0>(dRow, xRow, bPl, cPl, yPl, a2n, Dv, ch, n, lp, ls);
    else       scan_body<1>(dRow, xRow, bPl, cPl, yPl, a2n, Dv, ch, n, lp, ls);
}

// ---- kE: 4-dir combine + LayerNorm over D ----------------------------------
__global__ __launch_bounds__(256) void kE(const float* __restrict__ y,
                                          const float* __restrict__ lnw,
                                          const float* __restrict__ lnb,
                                          float* __restrict__ out) {
    const int wave = threadIdx.x >> 6, lane = threadIdx.x & 63;
    const int p = blockIdx.x * 4 + wave;
    const int hh = p / 96, ww = p % 96;
    const int pT = ww * 96 + hh;
    const float* y0 = y;
    const float* y1 = y + 1L * cL * 96;
    const float* y2 = y + 2L * cL * 96;
    const float* y3 = y + 3L * cL * 96;

    float v0, v1 = 0.f, s = 0.f, s2 = 0.f;
    v0 = y0[(long)p * 96 + lane] + y2[(long)p * 96 + lane]
       + y1[(long)pT * 96 + lane] + y3[(long)pT * 96 + lane];
    s += v0; s2 += v0 * v0;
    if (lane < 32) {
        int d2 = lane + 64;
        v1 = y0[(long)p * 96 + d2] + y2[(long)p * 96 + d2]
           + y1[(long)pT * 96 + d2] + y3[(long)pT * 96 + d2];
        s += v1; s2 += v1 * v1;
    }
    #pragma unroll
    for (int m = 32; m >= 1; m >>= 1) {
        s  += __shfl_xor(s,  m, 64);
        s2 += __shfl_xor(s2, m, 64);
    }
    const float mu = s * (1.f / 96.f);
    const float rstd = rsqrtf(s2 * (1.f / 96.f) - mu * mu + 1e-5f);
    out[(long)p * 96 + lane] = (v0 - mu) * rstd * lnw[lane] + lnb[lane];
    if (lane < 32)
        out[(long)p * 96 + 64 + lane] = (v1 - mu) * rstd * lnw[64 + lane] + lnb[64 + lane];
}

extern "C" void kernel_launch(void* const* d_in, const int* in_sizes, int n_in,
                              void* d_out, int out_size, void* d_ws, size_t ws_size,
                              hipStream_t stream) {
    const float* x    = (const float*)d_in[0];
    const float* xpw  = (const float*)d_in[1];
    const float* dtw  = (const float*)d_in[2];
    const float* dtb  = (const float*)d_in[3];
    const float* Alog = (const float*)d_in[4];
    const float* Dsv  = (const float*)d_in[5];
    const float* lnw  = (const float*)d_in[6];
    const float* lnb  = (const float*)d_in[7];
    float* ws = (float*)d_ws;

    float* xT    = ws + OFF_XT;
    float* delta = ws + OFF_DELTA;
    float* Bs    = ws + OFF_BS;
    float* Cs    = ws + OFF_CS;
    float* y     = ws + OFF_Y;
    float* out   = (float*)d_out;

    kT<<<dim3(3, 3, 96), 256, 0, stream>>>(x, xT);
    kA<<<dim3(144, 4), 256, 0, stream>>>(x, xT, xpw, dtw, dtb, delta, Bs, Cs);
    kS<<<cK * cD, 1024, 0, stream>>>(x, xT, delta, Bs, Cs, Alog, Dsv, y);
    kE<<<cL / 4, 256, 0, stream>>>(y, lnw, lnb, out);
}

// Round 7
// 128.096 us; speedup vs baseline: 1.1524x; 1.1524x over previous
//
#include <hip/hip_runtime.h>
#include <math.h>

// SS2D: B=1, D=96, H=W=96, L=9216, K=4, N=16, R=6
constexpr int cD = 96, cL = 9216, cK = 4;
constexpr float LOG2E = 1.44269504088896f;

// ws float offsets (~40 MB)
constexpr long OFF_XT    = 0;                       // [96][9216] transposed x
constexpr long OFF_DELTA = OFF_XT    + (long)cD*cL; // [K][96][9216] d-major, own raster
constexpr long OFF_BS    = OFF_DELTA + 4L*cD*cL;    // [K][9216][16]
constexpr long OFF_CS    = OFF_BS    + 4L*cL*16;    // [K][9216][16]
constexpr long OFF_Y     = OFF_CS    + 4L*cL*16;    // [K][96][9216] d-major, p-raster
constexpr long OFF_SUMP  = OFF_Y     + 4L*cD*cL;    // [384][64][16]
constexpr long OFF_SUMS  = OFF_SUMP  + 384L*64*16;  // [384][64][16]

// ---- kT: xT[d][w*96+h] = x[d][h*96+w] --------------------------------------
__global__ __launch_bounds__(256) void kT(const float* __restrict__ x,
                                          float* __restrict__ xT) {
    __shared__ float t[32][33];
    const int h0 = blockIdx.x * 32, w0 = blockIdx.y * 32, d = blockIdx.z;
    const float* xd = x + (long)d * cL;
    float* xtd = xT + (long)d * cL;
    for (int o = threadIdx.x; o < 1024; o += 256) {
        int i = o >> 5, j = o & 31;
        t[i][j] = xd[(h0 + i) * 96 + w0 + j];
    }
    __syncthreads();
    for (int o = threadIdx.x; o < 1024; o += 256) {
        int i = o >> 5, j = o & 31;
        xtd[(w0 + i) * 96 + h0 + j] = t[j][i];
    }
}

// ---- kA: G = W_k @ src_k; delta[k][d][p] (d-major), Bs/Cs[k][p][16] --------
__global__ __launch_bounds__(256) void kA(const float* __restrict__ x,
                                          const float* __restrict__ xT,
                                          const float* __restrict__ xpw,
                                          const float* __restrict__ dtw,
                                          const float* __restrict__ dtb,
                                          float* __restrict__ delta,
                                          float* __restrict__ Bs,
                                          float* __restrict__ Cs) {
    __shared__ float xs[96][64];
    __shared__ float xdbl[38][65];
    __shared__ float dtw_l[96 * 6];
    __shared__ float dtb_l[96];
    const int p0 = blockIdx.x * 64;
    const int k  = blockIdx.y;
    const int tid = threadIdx.x;
    const float* src = (k & 1) ? xT : x;

    for (int o = tid; o < 96 * 64; o += 256) {
        int dd = o >> 6, pp = o & 63;
        xs[dd][pp] = src[(long)dd * cL + p0 + pp];
    }
    for (int o = tid; o < 96 * 6; o += 256) dtw_l[o] = dtw[k * 96 * 6 + o];
    if (tid < 96) dtb_l[tid] = dtb[k * 96 + tid];
    __syncthreads();

    const int lane = tid & 63;
    const int c0 = __builtin_amdgcn_readfirstlane((tid >> 6) * 10);
    const float* wk = xpw + (long)k * 38 * 96;
    float acc[10];
    #pragma unroll
    for (int i = 0; i < 10; ++i) acc[i] = 0.f;
    #pragma unroll 4
    for (int dd = 0; dd < 96; ++dd) {
        float xv = xs[dd][lane];
        #pragma unroll
        for (int i = 0; i < 10; ++i) {
            int c = c0 + i; c = c > 37 ? 37 : c;
            acc[i] = fmaf(xv, wk[c * 96 + dd], acc[i]);
        }
    }
    #pragma unroll
    for (int i = 0; i < 10; ++i) {
        int c = c0 + i; c = c > 37 ? 37 : c;
        xdbl[c][lane] = acc[i];
    }
    __syncthreads();

    for (int o = tid; o < 64 * 16; o += 256) {
        int n = o & 15, pp = o >> 4;
        long idx = ((long)k * cL + p0 + pp) * 16 + n;
        Bs[idx] = xdbl[6 + n][pp];
        Cs[idx] = xdbl[22 + n][pp];
    }
    for (int o = tid; o < 96 * 64; o += 256) {
        int dd = o >> 6, pp = o & 63;
        float s = dtb_l[dd];
        #pragma unroll
        for (int r = 0; r < 6; ++r) s = fmaf(xdbl[r][pp], dtw_l[dd * 6 + r], s);
        float sp = fmaxf(s, 0.f) + __logf(1.f + __expf(-fabsf(s)));
        delta[((long)(k * 96 + dd)) * cL + p0 + pp] = sp;
    }
}

// ---- kS1: pass-1 chunk summaries. 768 blocks x 512 thr (32 ch x 16 n) ------
__global__ __launch_bounds__(512) void kS1(const float* __restrict__ x,
                                           const float* __restrict__ xT,
                                           const float* __restrict__ delta,
                                           const float* __restrict__ Bs,
                                           const float* __restrict__ Alog,
                                           float* __restrict__ Pg,
                                           float* __restrict__ Sg) {
    const int tid = threadIdx.x;
    const int n = tid & 15, chl = tid >> 4;
    const int hb = blockIdx.x & 1;
    const int seq = blockIdx.x >> 1;          // k*96+d
    const int k = seq / 96, d = seq % 96;
    const int rev = k >> 1;
    const int ch = hb * 32 + chl;
    const float* srcx = (k & 1) ? xT : x;
    const float a2n = -LOG2E * exp2f(LOG2E * Alog[(long)seq * 16 + n]);
    const int qb = rev ? (9215 - ch * 144) : ch * 144;
    const float* dRow = delta + (long)seq * cL;
    const float* xRow = srcx + (long)d * cL;
    const float* bP = Bs + ((long)k * cL + qb) * 16 + n;

    float h = 0.f, sdl = 0.f;
#define ST1(DL, XV, BOFF) { float bv = b[BOFF]; float e = exp2f((DL) * a2n); \
                            h = fmaf(e, h, (DL) * (XV) * bv); sdl += (DL); }
    if (!rev) {
        const float4* dp = (const float4*)(dRow + qb);
        const float4* xp = (const float4*)(xRow + qb);
        for (int g = 0; g < 36; ++g) {
            float4 d4 = dp[g], x4 = xp[g];
            const float* b = bP + (long)g * 64;
            ST1(d4.x, x4.x, 0)  ST1(d4.y, x4.y, 16)
            ST1(d4.z, x4.z, 32) ST1(d4.w, x4.w, 48)
        }
    } else {
        const float4* dp = (const float4*)(dRow + qb - 3);
        const float4* xp = (const float4*)(xRow + qb - 3);
        for (int g = 0; g < 36; ++g) {
            float4 d4 = dp[-g], x4 = xp[-g];
            const float* b = bP - (long)g * 64;
            ST1(d4.w, x4.w, 0)   ST1(d4.z, x4.z, -16)
            ST1(d4.y, x4.y, -32) ST1(d4.x, x4.x, -48)
        }
    }
#undef ST1
    long o = ((long)seq * 64 + ch) * 16 + n;
    Pg[o] = exp2f(a2n * sdl);
    Sg[o] = h;
}

// ---- kS2: in-LDS scan of 64 summaries + replay + transposed writeout -------
__global__ __launch_bounds__(512) void kS2(const float* __restrict__ x,
                                           const float* __restrict__ xT,
                                           const float* __restrict__ delta,
                                           const float* __restrict__ Bs,
                                           const float* __restrict__ Cs,
                                           const float* __restrict__ Alog,
                                           const float* __restrict__ Dsv,
                                           const float* __restrict__ Pg,
                                           const float* __restrict__ Sg,
                                           float* __restrict__ y) {
    __shared__ float lp[64][16];
    __shared__ float ls[64][16];
    __shared__ float ybuf[4608 + 48];
    const int tid = threadIdx.x;
    const int n = tid & 15, chl = tid >> 4;
    const int hb = blockIdx.x & 1;
    const int seq = blockIdx.x >> 1;
    const int k = seq / 96, d = seq % 96;
    const int rev = k >> 1;
    const int ch = hb * 32 + chl;

    ((float*)lp)[tid]       = Pg[(long)seq * 1024 + tid];
    ((float*)lp)[tid + 512] = Pg[(long)seq * 1024 + tid + 512];
    ((float*)ls)[tid]       = Sg[(long)seq * 1024 + tid];
    ((float*)ls)[tid + 512] = Sg[(long)seq * 1024 + tid + 512];
    __syncthreads();
    #pragma unroll
    for (int off = 1; off < 64; off <<= 1) {
        const int c0 = tid >> 4, n0 = tid & 15;
        const int c1 = c0 + 32;
        float p0v = lp[c0][n0], s0v = ls[c0][n0];
        float p1v = lp[c1][n0], s1v = ls[c1][n0];
        float np0 = p0v, ns0 = s0v, np1 = p1v, ns1 = s1v;
        if (c0 >= off) { np0 = p0v * lp[c0 - off][n0]; ns0 = fmaf(p0v, ls[c0 - off][n0], s0v); }
        if (c1 >= off) { np1 = p1v * lp[c1 - off][n0]; ns1 = fmaf(p1v, ls[c1 - off][n0], s1v); }
        __syncthreads();
        lp[c0][n0] = np0; ls[c0][n0] = ns0;
        lp[c1][n0] = np1; ls[c1][n0] = ns1;
        __syncthreads();
    }
    float h = (ch == 0) ? 0.f : ls[ch - 1][n];

    const float* srcx = (k & 1) ? xT : x;
    const float a2n = -LOG2E * exp2f(LOG2E * Alog[(long)seq * 16 + n]);
    const float Dv = Dsv[seq];
    const int qb = rev ? (9215 - ch * 144) : ch * 144;
    const int sb = rev ? (1 - hb) * 4608 : hb * 4608;
    const float* dRow = delta + (long)seq * cL;
    const float* xRow = srcx + (long)d * cL;
    const float* bP = Bs + ((long)k * cL + qb) * 16 + n;
    const float* cP = Cs + ((long)k * cL + qb) * 16 + n;
    unsigned Pl = (unsigned)(qb - sb);

#define ST2(DL, XV, OFF) { float bv = b[OFF], cv = c[OFF];                    \
        float e = exp2f((DL) * a2n); h = fmaf(e, h, (DL) * (XV) * bv);        \
        float pv = h * cv;                                                    \
        pv += __shfl_xor(pv, 1, 16); pv += __shfl_xor(pv, 2, 16);             \
        pv += __shfl_xor(pv, 4, 16); pv += __shfl_xor(pv, 8, 16);             \
        if (n == 0) ybuf[Pl + Pl / 96u] = fmaf(Dv, (XV), pv); }
    if (!rev) {
        const float4* dp = (const float4*)(dRow + qb);
        const float4* xp = (const float4*)(xRow + qb);
        for (int g = 0; g < 36; ++g) {
            float4 d4 = dp[g], x4 = xp[g];
            const float* b = bP + (long)g * 64;
            const float* c = cP + (long)g * 64;
            ST2(d4.x, x4.x, 0)  Pl++;
            ST2(d4.y, x4.y, 16) Pl++;
            ST2(d4.z, x4.z, 32) Pl++;
            ST2(d4.w, x4.w, 48) Pl++;
        }
    } else {
        const float4* dp = (const float4*)(dRow + qb - 3);
        const float4* xp = (const float4*)(xRow + qb - 3);
        for (int g = 0; g < 36; ++g) {
            float4 d4 = dp[-g], x4 = xp[-g];
            const float* b = bP - (long)g * 64;
            const float* c = cP - (long)g * 64;
            ST2(d4.w, x4.w, 0)   Pl--;
            ST2(d4.z, x4.z, -16) Pl--;
            ST2(d4.y, x4.y, -32) Pl--;
            ST2(d4.x, x4.x, -48) Pl--;
        }
    }
#undef ST2
    __syncthreads();

    float* yrow = y + (long)seq * cL;
    if (k & 1) {
        const int w0 = sb / 96;
        for (int o = tid; o < 4608; o += 512) {
            int hh = o / 48, wl = o - hh * 48;
            yrow[hh * 96 + w0 + wl] = ybuf[wl * 97 + hh];
        }
    } else {
        for (int o = tid; o < 4608; o += 512) {
            yrow[sb + o] = ybuf[o + o / 96u];
        }
    }
}

// ---- kE: 4-dir sum (all p-raster, d-major) + LayerNorm; 32 p per block -----
__global__ __launch_bounds__(256) void kE(const float* __restrict__ y,
                                          const float* __restrict__ lnw,
                                          const float* __restrict__ lnb,
                                          float* __restrict__ out) {
    __shared__ float vs[96][36];
    __shared__ float red[8][32], red2[8][32];
    __shared__ float MU[32], RS[32];
    const int tid = threadIdx.x;
    const int p0 = blockIdx.x * 32;

    for (int o = tid; o < 96 * 8; o += 256) {
        int dd = o >> 3, j = o & 7;
        const float* r0 = y + (long)dd * cL + p0;
        const float* r1 = y + (long)(96 + dd) * cL + p0;
        const float* r2 = y + (long)(192 + dd) * cL + p0;
        const float* r3 = y + (long)(288 + dd) * cL + p0;
        float4 a = ((const float4*)r0)[j];
        float4 b = ((const float4*)r1)[j];
        float4 c = ((const float4*)r2)[j];
        float4 e = ((const float4*)r3)[j];
        *(float4*)&vs[dd][4 * j] = make_float4(a.x + b.x + c.x + e.x,
                                               a.y + b.y + c.y + e.y,
                                               a.z + b.z + c.z + e.z,
                                               a.w + b.w + c.w + e.w);
    }
    __syncthreads();

    const int p = tid & 31, part = tid >> 5;      // 8 parts x 12 d
    float s = 0.f, s2 = 0.f;
    for (int dd = part * 12; dd < part * 12 + 12; ++dd) {
        float v = vs[dd][p];
        s += v; s2 = fmaf(v, v, s2);
    }
    red[part][p] = s; red2[part][p] = s2;
    __syncthreads();
    if (tid < 32) {
        float S = 0.f, S2 = 0.f;
        #pragma unroll
        for (int q = 0; q < 8; ++q) { S += red[q][tid]; S2 += red2[q][tid]; }
        float m = S * (1.f / 96.f);
        MU[tid] = m;
        RS[tid] = rsqrtf(S2 * (1.f / 96.f) - m * m + 1e-5f);
    }
    __syncthreads();
    for (int o = tid; o < 32 * 96; o += 256) {
        int pl = o / 96, dd = o - pl * 96;
        out[(long)(p0 + pl) * 96 + dd] = (vs[dd][pl] - MU[pl]) * RS[pl] * lnw[dd] + lnb[dd];
    }
}

extern "C" void kernel_launch(void* const* d_in, const int* in_sizes, int n_in,
                              void* d_out, int out_size, void* d_ws, size_t ws_size,
                              hipStream_t stream) {
    const float* x    = (const float*)d_in[0];
    const float* xpw  = (const float*)d_in[1];
    const float* dtw  = (const float*)d_in[2];
    const float* dtb  = (const float*)d_in[3];
    const float* Alog = (const float*)d_in[4];
    const float* Dsv  = (const float*)d_in[5];
    const float* lnw  = (const float*)d_in[6];
    const float* lnb  = (const float*)d_in[7];
    float* ws = (float*)d_ws;

    float* xT    = ws + OFF_XT;
    float* delta = ws + OFF_DELTA;
    float* Bs    = ws + OFF_BS;
    float* Cs    = ws + OFF_CS;
    float* y     = ws + OFF_Y;
    float* Pg    = ws + OFF_SUMP;
    float* Sg    = ws + OFF_SUMS;
    float* out   = (float*)d_out;

    kT<<<dim3(3, 3, 96), 256, 0, stream>>>(x, xT);
    kA<<<dim3(144, 4), 256, 0, stream>>>(x, xT, xpw, dtw, dtb, delta, Bs, Cs);
    kS1<<<768, 512, 0, stream>>>(x, xT, delta, Bs, Alog, Pg, Sg);
    kS2<<<768, 512, 0, stream>>>(x, xT, delta, Bs, Cs, Alog, Dsv, Pg, Sg, y);
    kE<<<288, 256, 0, stream>>>(y, lnw, lnb, out);
}

// Round 8
// 110.343 us; speedup vs baseline: 1.3378x; 1.1609x over previous
//
#include <hip/hip_runtime.h>
#include <math.h>

// SS2D: B=1, D=96, H=W=96, L=9216, K=4, N=16, R=6
constexpr int cD = 96, cL = 9216, cK = 4;
constexpr int CL = 36, NCH = 256;       // 256 chunks of 36 per sequence
constexpr float LOG2E = 1.44269504088896f;

// ws float offsets
constexpr long OFF_XT    = 0;                       // [96][9216]
constexpr long OFF_DELTA = OFF_XT    + (long)cD*cL; // [K][96][9216] d-major
constexpr long OFF_BS    = OFF_DELTA + 4L*cD*cL;    // [K][9216][16]
constexpr long OFF_CS    = OFF_BS    + 4L*cL*16;    // [K][9216][16]
constexpr long OFF_Y     = OFF_CS    + 4L*cL*16;    // [K][96][9216] d-major raster
constexpr long OFF_SUMP  = OFF_Y     + 4L*cD*cL;    // [384][256][16]
constexpr long OFF_SUMS  = OFF_SUMP  + 384L*256*16; // [384][256][16]

__device__ __forceinline__ float4 a2prep(float4 v) {
    return make_float4(-LOG2E * exp2f(LOG2E * v.x), -LOG2E * exp2f(LOG2E * v.y),
                       -LOG2E * exp2f(LOG2E * v.z), -LOG2E * exp2f(LOG2E * v.w));
}

// ---- kT: xT[d][w*96+h] = x[d][h*96+w] --------------------------------------
__global__ __launch_bounds__(256) void kT(const float* __restrict__ x,
                                          float* __restrict__ xT) {
    __shared__ float t[32][33];
    const int h0 = blockIdx.x * 32, w0 = blockIdx.y * 32, d = blockIdx.z;
    const float* xd = x + (long)d * cL;
    float* xtd = xT + (long)d * cL;
    for (int o = threadIdx.x; o < 1024; o += 256) {
        int i = o >> 5, j = o & 31;
        t[i][j] = xd[(h0 + i) * 96 + w0 + j];
    }
    __syncthreads();
    for (int o = threadIdx.x; o < 1024; o += 256) {
        int i = o >> 5, j = o & 31;
        xtd[(w0 + i) * 96 + h0 + j] = t[j][i];
    }
}

// ---- kA: G = W_k @ src_k; delta[k][d][p] (d-major), Bs/Cs[k][p][16] --------
__global__ __launch_bounds__(256) void kA(const float* __restrict__ x,
                                          const float* __restrict__ xT,
                                          const float* __restrict__ xpw,
                                          const float* __restrict__ dtw,
                                          const float* __restrict__ dtb,
                                          float* __restrict__ delta,
                                          float* __restrict__ Bs,
                                          float* __restrict__ Cs) {
    __shared__ float xs[96][64];
    __shared__ float xdbl[38][65];
    __shared__ float dtw_l[96 * 6];
    __shared__ float dtb_l[96];
    const int p0 = blockIdx.x * 64;
    const int k  = blockIdx.y;
    const int tid = threadIdx.x;
    const float* src = (k & 1) ? xT : x;

    for (int o = tid; o < 96 * 64; o += 256) {
        int dd = o >> 6, pp = o & 63;
        xs[dd][pp] = src[(long)dd * cL + p0 + pp];
    }
    for (int o = tid; o < 96 * 6; o += 256) dtw_l[o] = dtw[k * 96 * 6 + o];
    if (tid < 96) dtb_l[tid] = dtb[k * 96 + tid];
    __syncthreads();

    const int lane = tid & 63;
    const int c0 = __builtin_amdgcn_readfirstlane((tid >> 6) * 10);
    const float* wk = xpw + (long)k * 38 * 96;
    float acc[10];
    #pragma unroll
    for (int i = 0; i < 10; ++i) acc[i] = 0.f;
    #pragma unroll 4
    for (int dd = 0; dd < 96; ++dd) {
        float xv = xs[dd][lane];
        #pragma unroll
        for (int i = 0; i < 10; ++i) {
            int c = c0 + i; c = c > 37 ? 37 : c;
            acc[i] = fmaf(xv, wk[c * 96 + dd], acc[i]);
        }
    }
    #pragma unroll
    for (int i = 0; i < 10; ++i) {
        int c = c0 + i; c = c > 37 ? 37 : c;
        xdbl[c][lane] = acc[i];
    }
    __syncthreads();

    for (int o = tid; o < 64 * 16; o += 256) {
        int n = o & 15, pp = o >> 4;
        long idx = ((long)k * cL + p0 + pp) * 16 + n;
        Bs[idx] = xdbl[6 + n][pp];
        Cs[idx] = xdbl[22 + n][pp];
    }
    for (int o = tid; o < 96 * 64; o += 256) {
        int dd = o >> 6, pp = o & 63;
        float s = dtb_l[dd];
        #pragma unroll
        for (int r = 0; r < 6; ++r) s = fmaf(xdbl[r][pp], dtw_l[dd * 6 + r], s);
        float sp = fmaxf(s, 0.f) + __logf(1.f + __expf(-fabsf(s)));
        delta[((long)(k * 96 + dd)) * cL + p0 + pp] = sp;
    }
}

// ---- kS1: chunk summaries; 4 lanes/chunk, 4 n per lane ---------------------
template<int REV>
__device__ __forceinline__ void sum_chunk(const float* __restrict__ dB,
                                          const float* __restrict__ xB,
                                          const float* __restrict__ bB,
                                          float4 a2, float4& hO, float& sdlO) {
    float4 h = make_float4(0.f, 0.f, 0.f, 0.f);
    float sdl = 0.f;
#define S1(DL, XV, OFF) { \
        float4 B = *(const float4*)(REV ? bB - (OFF)*16 : bB + (OFF)*16); \
        float t = (DL) * (XV); sdl += (DL); \
        h.x = fmaf(exp2f((DL)*a2.x), h.x, t*B.x); \
        h.y = fmaf(exp2f((DL)*a2.y), h.y, t*B.y); \
        h.z = fmaf(exp2f((DL)*a2.z), h.z, t*B.z); \
        h.w = fmaf(exp2f((DL)*a2.w), h.w, t*B.w); }
    #pragma unroll
    for (int g = 0; g < 9; ++g) {
        float4 d4 = *(const float4*)(REV ? dB - 4*g - 3 : dB + 4*g);
        float4 x4 = *(const float4*)(REV ? xB - 4*g - 3 : xB + 4*g);
        if (!REV) { S1(d4.x,x4.x,4*g) S1(d4.y,x4.y,4*g+1) S1(d4.z,x4.z,4*g+2) S1(d4.w,x4.w,4*g+3) }
        else      { S1(d4.w,x4.w,4*g) S1(d4.z,x4.z,4*g+1) S1(d4.y,x4.y,4*g+2) S1(d4.x,x4.x,4*g+3) }
    }
#undef S1
    hO = h; sdlO = sdl;
}

__global__ __launch_bounds__(512) void kS1(const float* __restrict__ x,
                                           const float* __restrict__ xT,
                                           const float* __restrict__ delta,
                                           const float* __restrict__ Bs,
                                           const float* __restrict__ Alog,
                                           float* __restrict__ Pg,
                                           float* __restrict__ Sg) {
    const int tid = threadIdx.x;
    const int n0 = (tid & 3) * 4, chl = tid >> 2;
    const int hb = blockIdx.x & 1, seq = blockIdx.x >> 1;
    const int k = seq / 96, d = seq % 96, rev = k >> 1;
    const int ch = hb * 128 + chl;
    const int q0 = rev ? (9215 - ch * CL) : ch * CL;

    const float4 a2 = a2prep(*(const float4*)(Alog + (long)seq * 16 + n0));
    const float* dB = delta + (long)seq * cL + q0;
    const float* xB = ((k & 1) ? xT : x) + (long)d * cL + q0;
    const float* bB = Bs + ((long)k * cL + q0) * 16 + n0;

    float4 h; float sdl;
    if (!rev) sum_chunk<0>(dB, xB, bB, a2, h, sdl);
    else      sum_chunk<1>(dB, xB, bB, a2, h, sdl);

    long o = ((long)seq * NCH + ch) * 16 + n0;
    *(float4*)(Pg + o) = make_float4(exp2f(a2.x*sdl), exp2f(a2.y*sdl),
                                     exp2f(a2.z*sdl), exp2f(a2.w*sdl));
    *(float4*)(Sg + o) = h;
}

// ---- kS2: in-LDS hierarchical scan of 256 summaries + replay + writeout ----
__global__ __launch_bounds__(512) void kS2(const float* __restrict__ x,
                                           const float* __restrict__ xT,
                                           const float* __restrict__ delta,
                                           const float* __restrict__ Bs,
                                           const float* __restrict__ Cs,
                                           const float* __restrict__ Alog,
                                           const float* __restrict__ Dsv,
                                           const float* __restrict__ Pg,
                                           const float* __restrict__ Sg,
                                           float* __restrict__ y) {
    __shared__ float lp[NCH][16];
    __shared__ float ls[NCH][16];
    __shared__ float ybuf[4608 + 48];
    float* gpf = &lp[0][0];           // aliased after phase A (gp: [0,512), gs: [512,1024))
    const int tid = threadIdx.x;
    const int hb = blockIdx.x & 1, seq = blockIdx.x >> 1;
    const int k = seq / 96, d = seq % 96, rev = k >> 1;

    #pragma unroll
    for (int i = 0; i < 8; ++i) {
        ((float*)lp)[tid + i * 512] = Pg[(long)seq * 4096 + tid + i * 512];
        ((float*)ls)[tid + i * 512] = Sg[(long)seq * 4096 + tid + i * 512];
    }
    __syncthreads();

    // phase A: serial scan of 8 consecutive chunks per thread (sg, sn)
    const int sn = tid & 15, sg = tid >> 4;     // sg in [0,32)
    float LPe[8], LSe[8];
    {
        float P = 1.f, S = 0.f;
        #pragma unroll
        for (int i = 0; i < 8; ++i) {
            LPe[i] = P; LSe[i] = S;
            float p = lp[sg * 8 + i][sn], s = ls[sg * 8 + i][sn];
            S = fmaf(p, S, s); P = p * P;
        }
        __syncthreads();                        // all phase-A reads done
        gpf[tid] = P; gpf[512 + tid] = S;       // group summaries over lp's storage
    }
    __syncthreads();
    // phase B: Kogge-Stone over 32 groups (1 elem/thread)
    #pragma unroll
    for (int off = 1; off < 32; off <<= 1) {
        float pc = gpf[tid], sc = gpf[512 + tid];
        float pn = pc, snn = sc;
        if (sg >= off) {
            pn  = pc * gpf[(sg - off) * 16 + sn];
            snn = fmaf(pc, gpf[512 + (sg - off) * 16 + sn], sc);
        }
        __syncthreads();
        gpf[tid] = pn; gpf[512 + tid] = snn;
        __syncthreads();
    }
    const float GS = (sg == 0) ? 0.f : gpf[512 + (sg - 1) * 16 + sn];
    // phase C: exclusive per-chunk init -> ls
    #pragma unroll
    for (int i = 0; i < 8; ++i) ls[sg * 8 + i][sn] = fmaf(LPe[i], GS, LSe[i]);
    __syncthreads();

    // replay
    const int n0 = (tid & 3) * 4, chl = tid >> 2;
    const int ch = hb * 128 + chl;
    const int q0 = rev ? (9215 - ch * CL) : ch * CL;
    const float4 a2 = a2prep(*(const float4*)(Alog + (long)seq * 16 + n0));
    const float Dv = Dsv[seq];
    const float* dB = delta + (long)seq * cL + q0;
    const float* xB = ((k & 1) ? xT : x) + (long)d * cL + q0;
    const float* bB = Bs + ((long)k * cL + q0) * 16 + n0;
    const float* cB = Cs + ((long)k * cL + q0) * 16 + n0;
    float4 h = *(float4*)&ls[ch][n0];
    const int slB = chl * CL;
    const bool lane0 = (tid & 3) == 0;

#define S2(RV, DL, XV, OFF) { \
        float4 B = *(const float4*)(RV ? bB - (OFF)*16 : bB + (OFF)*16); \
        float4 C = *(const float4*)(RV ? cB - (OFF)*16 : cB + (OFF)*16); \
        float t = (DL) * (XV); \
        h.x = fmaf(exp2f((DL)*a2.x), h.x, t*B.x); \
        h.y = fmaf(exp2f((DL)*a2.y), h.y, t*B.y); \
        h.z = fmaf(exp2f((DL)*a2.z), h.z, t*B.z); \
        h.w = fmaf(exp2f((DL)*a2.w), h.w, t*B.w); \
        float pv = fmaf(h.x, C.x, fmaf(h.y, C.y, fmaf(h.z, C.z, h.w * C.w))); \
        pv += __shfl_xor(pv, 1, 4); \
        pv += __shfl_xor(pv, 2, 4); \
        if (lane0) { int sl = slB + (OFF); int yloc = RV ? 4607 - sl : sl; \
                     ybuf[yloc + yloc / 96] = fmaf(Dv, (XV), pv); } }
    if (!rev) {
        #pragma unroll
        for (int g = 0; g < 9; ++g) {
            float4 d4 = *(const float4*)(dB + 4*g);
            float4 x4 = *(const float4*)(xB + 4*g);
            S2(0, d4.x, x4.x, 4*g)   S2(0, d4.y, x4.y, 4*g+1)
            S2(0, d4.z, x4.z, 4*g+2) S2(0, d4.w, x4.w, 4*g+3)
        }
    } else {
        #pragma unroll
        for (int g = 0; g < 9; ++g) {
            float4 d4 = *(const float4*)(dB - 4*g - 3);
            float4 x4 = *(const float4*)(xB - 4*g - 3);
            S2(1, d4.w, x4.w, 4*g)   S2(1, d4.z, x4.z, 4*g+1)
            S2(1, d4.y, x4.y, 4*g+2) S2(1, d4.x, x4.x, 4*g+3)
        }
    }
#undef S2
    __syncthreads();

    // writeout (ybuf holds local-q-ordered 4608 values with +q/96 pad)
    const int sb = rev ? (1 - hb) * 4608 : hb * 4608;
    float* yrow = y + (long)seq * cL;
    if (k & 1) {
        const int w0 = sb / 96;
        for (int o = tid; o < 4608; o += 512) {
            int hh = o / 48, wl = o - hh * 48;
            yrow[hh * 96 + w0 + wl] = ybuf[wl * 97 + hh];
        }
    } else {
        for (int o = tid; o < 4608; o += 512) {
            yrow[sb + o] = ybuf[o + o / 96];
        }
    }
}

// ---- kE: 4-dir sum (all raster, d-major) + LayerNorm; 32 p per block -------
__global__ __launch_bounds__(256) void kE(const float* __restrict__ y,
                                          const float* __restrict__ lnw,
                                          const float* __restrict__ lnb,
                                          float* __restrict__ out) {
    __shared__ float vs[96][36];
    __shared__ float red[8][32], red2[8][32];
    __shared__ float MU[32], RS[32];
    const int tid = threadIdx.x;
    const int p0 = blockIdx.x * 32;

    for (int o = tid; o < 96 * 8; o += 256) {
        int dd = o >> 3, j = o & 7;
        const float* r0 = y + (long)dd * cL + p0;
        const float* r1 = y + (long)(96 + dd) * cL + p0;
        const float* r2 = y + (long)(192 + dd) * cL + p0;
        const float* r3 = y + (long)(288 + dd) * cL + p0;
        float4 a = ((const float4*)r0)[j];
        float4 b = ((const float4*)r1)[j];
        float4 c = ((const float4*)r2)[j];
        float4 e = ((const float4*)r3)[j];
        *(float4*)&vs[dd][4 * j] = make_float4(a.x + b.x + c.x + e.x,
                                               a.y + b.y + c.y + e.y,
                                               a.z + b.z + c.z + e.z,
                                               a.w + b.w + c.w + e.w);
    }
    __syncthreads();

    const int p = tid & 31, part = tid >> 5;
    float s = 0.f, s2 = 0.f;
    for (int dd = part * 12; dd < part * 12 + 12; ++dd) {
        float v = vs[dd][p];
        s += v; s2 = fmaf(v, v, s2);
    }
    red[part][p] = s; red2[part][p] = s2;
    __syncthreads();
    if (tid < 32) {
        float S = 0.f, S2 = 0.f;
        #pragma unroll
        for (int q = 0; q < 8; ++q) { S += red[q][tid]; S2 += red2[q][tid]; }
        float m = S * (1.f / 96.f);
        MU[tid] = m;
        RS[tid] = rsqrtf(S2 * (1.f / 96.f) - m * m + 1e-5f);
    }
    __syncthreads();
    for (int o = tid; o < 32 * 96; o += 256) {
        int pl = o / 96, dd = o - pl * 96;
        out[(long)(p0 + pl) * 96 + dd] = (vs[dd][pl] - MU[pl]) * RS[pl] * lnw[dd] + lnb[dd];
    }
}

extern "C" void kernel_launch(void* const* d_in, const int* in_sizes, int n_in,
                              void* d_out, int out_size, void* d_ws, size_t ws_size,
                              hipStream_t stream) {
    const float* x    = (const float*)d_in[0];
    const float* xpw  = (const float*)d_in[1];
    const float* dtw  = (const float*)d_in[2];
    const float* dtb  = (const float*)d_in[3];
    const float* Alog = (const float*)d_in[4];
    const float* Dsv  = (const float*)d_in[5];
    const float* lnw  = (const float*)d_in[6];
    const float* lnb  = (const float*)d_in[7];
    float* ws = (float*)d_ws;

    float* xT    = ws + OFF_XT;
    float* delta = ws + OFF_DELTA;
    float* Bs    = ws + OFF_BS;
    float* Cs    = ws + OFF_CS;
    float* y     = ws + OFF_Y;
    float* Pg    = ws + OFF_SUMP;
    float* Sg    = ws + OFF_SUMS;
    float* out   = (float*)d_out;

    kT<<<dim3(3, 3, 96), 256, 0, stream>>>(x, xT);
    kA<<<dim3(144, 4), 256, 0, stream>>>(x, xT, xpw, dtw, dtb, delta, Bs, Cs);
    kS1<<<768, 512, 0, stream>>>(x, xT, delta, Bs, Alog, Pg, Sg);
    kS2<<<768, 512, 0, stream>>>(x, xT, delta, Bs, Cs, Alog, Dsv, Pg, Sg, y);
    kE<<<288, 256, 0, stream>>>(y, lnw, lnb, out);
}

// Round 9
// 100.344 us; speedup vs baseline: 1.4711x; 1.0997x over previous
//
#include <hip/hip_runtime.h>
#include <math.h>

// SS2D: B=1, D=96, H=W=96, L=9216, K=4, N=16, R=6
constexpr int cD = 96, cL = 9216, cK = 4;
constexpr int CL = 36, NCH = 256;       // 256 chunks of 36 per sequence
constexpr float LOG2E = 1.44269504088896f;

// ws float offsets
constexpr long OFF_XT    = 0;                       // [96][9216]
constexpr long OFF_DELTA = OFF_XT    + (long)cD*cL; // [K][96][9216] d-major
constexpr long OFF_BS    = OFF_DELTA + 4L*cD*cL;    // [K][36][256][16] j-major!
constexpr long OFF_CS    = OFF_BS    + 4L*cL*16;    // [K][36][256][16]
constexpr long OFF_Y     = OFF_CS    + 4L*cL*16;    // [K][96][9216] d-major raster
constexpr long OFF_SUMP  = OFF_Y     + 4L*cD*cL;    // [384][256][16]
constexpr long OFF_SUMS  = OFF_SUMP  + 384L*256*16; // [384][256][16]

__device__ __forceinline__ float4 a2prep(float4 v) {
    return make_float4(-LOG2E * exp2f(LOG2E * v.x), -LOG2E * exp2f(LOG2E * v.y),
                       -LOG2E * exp2f(LOG2E * v.z), -LOG2E * exp2f(LOG2E * v.w));
}

// ---- kT: xT[d][w*96+h] = x[d][h*96+w] --------------------------------------
__global__ __launch_bounds__(256) void kT(const float* __restrict__ x,
                                          float* __restrict__ xT) {
    __shared__ float t[32][33];
    const int h0 = blockIdx.x * 32, w0 = blockIdx.y * 32, d = blockIdx.z;
    const float* xd = x + (long)d * cL;
    float* xtd = xT + (long)d * cL;
    for (int o = threadIdx.x; o < 1024; o += 256) {
        int i = o >> 5, j = o & 31;
        t[i][j] = xd[(h0 + i) * 96 + w0 + j];
    }
    __syncthreads();
    for (int o = threadIdx.x; o < 1024; o += 256) {
        int i = o >> 5, j = o & 31;
        xtd[(w0 + i) * 96 + h0 + j] = t[j][i];
    }
}

// ---- kA: G = W_k @ src_k; delta[k][d][p], Bs/Cs[k][36][256][16] ------------
__global__ __launch_bounds__(256) void kA(const float* __restrict__ x,
                                          const float* __restrict__ xT,
                                          const float* __restrict__ xpw,
                                          const float* __restrict__ dtw,
                                          const float* __restrict__ dtb,
                                          float* __restrict__ delta,
                                          float* __restrict__ Bs,
                                          float* __restrict__ Cs) {
    __shared__ float xs[96][64];
    __shared__ float xdbl[38][65];
    __shared__ float dtw_l[96 * 6];
    __shared__ float dtb_l[96];
    const int p0 = blockIdx.x * 64;
    const int k  = blockIdx.y;
    const int tid = threadIdx.x;
    const float* src = (k & 1) ? xT : x;

    for (int o = tid; o < 96 * 64; o += 256) {
        int dd = o >> 6, pp = o & 63;
        xs[dd][pp] = src[(long)dd * cL + p0 + pp];
    }
    for (int o = tid; o < 96 * 6; o += 256) dtw_l[o] = dtw[k * 96 * 6 + o];
    if (tid < 96) dtb_l[tid] = dtb[k * 96 + tid];
    __syncthreads();

    const int lane = tid & 63;
    const int c0 = __builtin_amdgcn_readfirstlane((tid >> 6) * 10);
    const float* wk = xpw + (long)k * 38 * 96;
    float acc[10];
    #pragma unroll
    for (int i = 0; i < 10; ++i) acc[i] = 0.f;
    #pragma unroll 4
    for (int dd = 0; dd < 96; ++dd) {
        float xv = xs[dd][lane];
        #pragma unroll
        for (int i = 0; i < 10; ++i) {
            int c = c0 + i; c = c > 37 ? 37 : c;
            acc[i] = fmaf(xv, wk[c * 96 + dd], acc[i]);
        }
    }
    #pragma unroll
    for (int i = 0; i < 10; ++i) {
        int c = c0 + i; c = c > 37 ? 37 : c;
        xdbl[c][lane] = acc[i];
    }
    __syncthreads();

    // Bs/Cs in scan-chunk-major layout: q = scan index, (ch,j)=(q/36,q%36)
    for (int o = tid; o < 64 * 16; o += 256) {
        int n = o & 15, pp = o >> 4;
        int P = p0 + pp;
        int q = (k < 2) ? P : (9215 - P);
        int ch = q / 36, j = q - ch * 36;
        long idx = (((long)k * 36 + j) * 256 + ch) * 16 + n;
        Bs[idx] = xdbl[6 + n][pp];
        Cs[idx] = xdbl[22 + n][pp];
    }
    for (int o = tid; o < 96 * 64; o += 256) {
        int dd = o >> 6, pp = o & 63;
        float s = dtb_l[dd];
        #pragma unroll
        for (int r = 0; r < 6; ++r) s = fmaf(xdbl[r][pp], dtw_l[dd * 6 + r], s);
        float sp = fmaxf(s, 0.f) + __logf(1.f + __expf(-fabsf(s)));
        delta[((long)(k * 96 + dd)) * cL + p0 + pp] = sp;
    }
}

// ---- kS1: chunk summaries; 4 lanes/chunk, 4 n per lane ---------------------
template<int REV>
__device__ __forceinline__ void sum_chunk(const float* __restrict__ dB,
                                          const float* __restrict__ xB,
                                          const float* __restrict__ bB,
                                          float4 a2, float4& hO, float& sdlO) {
    float4 h = make_float4(0.f, 0.f, 0.f, 0.f);
    float sdl = 0.f;
#define S1(DL, XV, OFF) { \
        float4 B = *(const float4*)(bB + (OFF) * 4096); \
        float t = (DL) * (XV); sdl += (DL); \
        h.x = fmaf(exp2f((DL)*a2.x), h.x, t*B.x); \
        h.y = fmaf(exp2f((DL)*a2.y), h.y, t*B.y); \
        h.z = fmaf(exp2f((DL)*a2.z), h.z, t*B.z); \
        h.w = fmaf(exp2f((DL)*a2.w), h.w, t*B.w); }
    #pragma unroll
    for (int g = 0; g < 9; ++g) {
        float4 d4 = *(const float4*)(REV ? dB - 4*g - 3 : dB + 4*g);
        float4 x4 = *(const float4*)(REV ? xB - 4*g - 3 : xB + 4*g);
        if (!REV) { S1(d4.x,x4.x,4*g) S1(d4.y,x4.y,4*g+1) S1(d4.z,x4.z,4*g+2) S1(d4.w,x4.w,4*g+3) }
        else      { S1(d4.w,x4.w,4*g) S1(d4.z,x4.z,4*g+1) S1(d4.y,x4.y,4*g+2) S1(d4.x,x4.x,4*g+3) }
    }
#undef S1
    hO = h; sdlO = sdl;
}

__global__ __launch_bounds__(512, 6) void kS1(const float* __restrict__ x,
                                              const float* __restrict__ xT,
                                              const float* __restrict__ delta,
                                              const float* __restrict__ Bs,
                                              const float* __restrict__ Alog,
                                              float* __restrict__ Pg,
                                              float* __restrict__ Sg) {
    const int tid = threadIdx.x;
    const int n0 = (tid & 3) * 4, chl = tid >> 2;
    const int hb = blockIdx.x & 1, seq = blockIdx.x >> 1;
    const int k = seq / 96, d = seq % 96, rev = k >> 1;
    const int ch = hb * 128 + chl;
    const int q0 = rev ? (9215 - ch * CL) : ch * CL;

    const float4 a2 = a2prep(*(const float4*)(Alog + (long)seq * 16 + n0));
    const float* dB = delta + (long)seq * cL + q0;
    const float* xB = ((k & 1) ? xT : x) + (long)d * cL + q0;
    const float* bB = Bs + (long)k * 36 * 4096 + (long)ch * 16 + n0;

    float4 h; float sdl;
    if (!rev) sum_chunk<0>(dB, xB, bB, a2, h, sdl);
    else      sum_chunk<1>(dB, xB, bB, a2, h, sdl);

    long o = ((long)seq * NCH + ch) * 16 + n0;
    *(float4*)(Pg + o) = make_float4(exp2f(a2.x*sdl), exp2f(a2.y*sdl),
                                     exp2f(a2.z*sdl), exp2f(a2.w*sdl));
    *(float4*)(Sg + o) = h;
}

// ---- kS2: in-LDS hierarchical scan of 256 summaries + replay + writeout ----
__global__ __launch_bounds__(512, 6) void kS2(const float* __restrict__ x,
                                              const float* __restrict__ xT,
                                              const float* __restrict__ delta,
                                              const float* __restrict__ Bs,
                                              const float* __restrict__ Cs,
                                              const float* __restrict__ Alog,
                                              const float* __restrict__ Dsv,
                                              const float* __restrict__ Pg,
                                              const float* __restrict__ Sg,
                                              float* __restrict__ y) {
    __shared__ float lp[NCH][16];
    __shared__ float ls[NCH][16];
    __shared__ float ybuf[4608 + 48];
    float* gpf = &lp[0][0];           // aliased after phase A
    const int tid = threadIdx.x;
    const int hb = blockIdx.x & 1, seq = blockIdx.x >> 1;
    const int k = seq / 96, d = seq % 96, rev = k >> 1;

    #pragma unroll
    for (int i = 0; i < 8; ++i) {
        ((float*)lp)[tid + i * 512] = Pg[(long)seq * 4096 + tid + i * 512];
        ((float*)ls)[tid + i * 512] = Sg[(long)seq * 4096 + tid + i * 512];
    }
    __syncthreads();

    // phase A: serial scan of 8 consecutive chunks per thread
    const int sn = tid & 15, sg = tid >> 4;     // sg in [0,32)
    float LPe[8], LSe[8];
    {
        float P = 1.f, S = 0.f;
        #pragma unroll
        for (int i = 0; i < 8; ++i) {
            LPe[i] = P; LSe[i] = S;
            float p = lp[sg * 8 + i][sn], s = ls[sg * 8 + i][sn];
            S = fmaf(p, S, s); P = p * P;
        }
        __syncthreads();
        gpf[tid] = P; gpf[512 + tid] = S;
    }
    __syncthreads();
    // phase B: Kogge-Stone over 32 groups
    #pragma unroll
    for (int off = 1; off < 32; off <<= 1) {
        float pc = gpf[tid], sc = gpf[512 + tid];
        float pn = pc, snn = sc;
        if (sg >= off) {
            pn  = pc * gpf[(sg - off) * 16 + sn];
            snn = fmaf(pc, gpf[512 + (sg - off) * 16 + sn], sc);
        }
        __syncthreads();
        gpf[tid] = pn; gpf[512 + tid] = snn;
        __syncthreads();
    }
    const float GS = (sg == 0) ? 0.f : gpf[512 + (sg - 1) * 16 + sn];
    // phase C: exclusive per-chunk init -> ls
    #pragma unroll
    for (int i = 0; i < 8; ++i) ls[sg * 8 + i][sn] = fmaf(LPe[i], GS, LSe[i]);
    __syncthreads();

    // replay
    const int n0 = (tid & 3) * 4, chl = tid >> 2;
    const int ch = hb * 128 + chl;
    const int q0 = rev ? (9215 - ch * CL) : ch * CL;
    const float4 a2 = a2prep(*(const float4*)(Alog + (long)seq * 16 + n0));
    const float Dv = Dsv[seq];
    const float* dB = delta + (long)seq * cL + q0;
    const float* xB = ((k & 1) ? xT : x) + (long)d * cL + q0;
    const float* bB = Bs + (long)k * 36 * 4096 + (long)ch * 16 + n0;
    const float* cB = Cs + (long)k * 36 * 4096 + (long)ch * 16 + n0;
    float4 h = *(float4*)&ls[ch][n0];
    const int slB = chl * CL;
    const bool lane0 = (tid & 3) == 0;

#define S2(RV, DL, XV, OFF) { \
        float4 B = *(const float4*)(bB + (OFF) * 4096); \
        float4 C = *(const float4*)(cB + (OFF) * 4096); \
        float t = (DL) * (XV); \
        h.x = fmaf(exp2f((DL)*a2.x), h.x, t*B.x); \
        h.y = fmaf(exp2f((DL)*a2.y), h.y, t*B.y); \
        h.z = fmaf(exp2f((DL)*a2.z), h.z, t*B.z); \
        h.w = fmaf(exp2f((DL)*a2.w), h.w, t*B.w); \
        float pv = fmaf(h.x, C.x, fmaf(h.y, C.y, fmaf(h.z, C.z, h.w * C.w))); \
        pv += __shfl_xor(pv, 1, 4); \
        pv += __shfl_xor(pv, 2, 4); \
        if (lane0) { int sl = slB + (OFF); int yloc = RV ? 4607 - sl : sl; \
                     ybuf[yloc + yloc / 96] = fmaf(Dv, (XV), pv); } }
    if (!rev) {
        #pragma unroll
        for (int g = 0; g < 9; ++g) {
            float4 d4 = *(const float4*)(dB + 4*g);
            float4 x4 = *(const float4*)(xB + 4*g);
            S2(0, d4.x, x4.x, 4*g)   S2(0, d4.y, x4.y, 4*g+1)
            S2(0, d4.z, x4.z, 4*g+2) S2(0, d4.w, x4.w, 4*g+3)
        }
    } else {
        #pragma unroll
        for (int g = 0; g < 9; ++g) {
            float4 d4 = *(const float4*)(dB - 4*g - 3);
            float4 x4 = *(const float4*)(xB - 4*g - 3);
            S2(1, d4.w, x4.w, 4*g)   S2(1, d4.z, x4.z, 4*g+1)
            S2(1, d4.y, x4.y, 4*g+2) S2(1, d4.x, x4.x, 4*g+3)
        }
    }
#undef S2
    __syncthreads();

    // writeout
    const int sb = rev ? (1 - hb) * 4608 : hb * 4608;
    float* yrow = y + (long)seq * cL;
    if (k & 1) {
        const int w0 = sb / 96;
        for (int o = tid; o < 4608; o += 512) {
            int hh = o / 48, wl = o - hh * 48;
            yrow[hh * 96 + w0 + wl] = ybuf[wl * 97 + hh];
        }
    } else {
        for (int o = tid; o < 4608; o += 512) {
            yrow[sb + o] = ybuf[o + o / 96];
        }
    }
}

// ---- kE: 4-dir sum (all raster, d-major) + LayerNorm; 32 p per block -------
__global__ __launch_bounds__(256) void kE(const float* __restrict__ y,
                                          const float* __restrict__ lnw,
                                          const float* __restrict__ lnb,
                                          float* __restrict__ out) {
    __shared__ float vs[96][36];
    __shared__ float red[8][32], red2[8][32];
    __shared__ float MU[32], RS[32];
    const int tid = threadIdx.x;
    const int p0 = blockIdx.x * 32;

    for (int o = tid; o < 96 * 8; o += 256) {
        int dd = o >> 3, j = o & 7;
        const float* r0 = y + (long)dd * cL + p0;
        const float* r1 = y + (long)(96 + dd) * cL + p0;
        const float* r2 = y + (long)(192 + dd) * cL + p0;
        const float* r3 = y + (long)(288 + dd) * cL + p0;
        float4 a = ((const float4*)r0)[j];
        float4 b = ((const float4*)r1)[j];
        float4 c = ((const float4*)r2)[j];
        float4 e = ((const float4*)r3)[j];
        *(float4*)&vs[dd][4 * j] = make_float4(a.x + b.x + c.x + e.x,
                                               a.y + b.y + c.y + e.y,
                                               a.z + b.z + c.z + e.z,
                                               a.w + b.w + c.w + e.w);
    }
    __syncthreads();

    const int p = tid & 31, part = tid >> 5;
    float s = 0.f, s2 = 0.f;
    for (int dd = part * 12; dd < part * 12 + 12; ++dd) {
        float v = vs[dd][p];
        s += v; s2 = fmaf(v, v, s2);
    }
    red[part][p] = s; red2[part][p] = s2;
    __syncthreads();
    if (tid < 32) {
        float S = 0.f, S2 = 0.f;
        #pragma unroll
        for (int q = 0; q < 8; ++q) { S += red[q][tid]; S2 += red2[q][tid]; }
        float m = S * (1.f / 96.f);
        MU[tid] = m;
        RS[tid] = rsqrtf(S2 * (1.f / 96.f) - m * m + 1e-5f);
    }
    __syncthreads();
    for (int o = tid; o < 32 * 96; o += 256) {
        int pl = o / 96, dd = o - pl * 96;
        out[(long)(p0 + pl) * 96 + dd] = (vs[dd][pl] - MU[pl]) * RS[pl] * lnw[dd] + lnb[dd];
    }
}

extern "C" void kernel_launch(void* const* d_in, const int* in_sizes, int n_in,
                              void* d_out, int out_size, void* d_ws, size_t ws_size,
                              hipStream_t stream) {
    const float* x    = (const float*)d_in[0];
    const float* xpw  = (const float*)d_in[1];
    const float* dtw  = (const float*)d_in[2];
    const float* dtb  = (const float*)d_in[3];
    const float* Alog = (const float*)d_in[4];
    const float* Dsv  = (const float*)d_in[5];
    const float* lnw  = (const float*)d_in[6];
    const float* lnb  = (const float*)d_in[7];
    float* ws = (float*)d_ws;

    float* xT    = ws + OFF_XT;
    float* delta = ws + OFF_DELTA;
    float* Bs    = ws + OFF_BS;
    float* Cs    = ws + OFF_CS;
    float* y     = ws + OFF_Y;
    float* Pg    = ws + OFF_SUMP;
    float* Sg    = ws + OFF_SUMS;
    float* out   = (float*)d_out;

    kT<<<dim3(3, 3, 96), 256, 0, stream>>>(x, xT);
    kA<<<dim3(144, 4), 256, 0, stream>>>(x, xT, xpw, dtw, dtb, delta, Bs, Cs);
    kS1<<<768, 512, 0, stream>>>(x, xT, delta, Bs, Alog, Pg, Sg);
    kS2<<<768, 512, 0, stream>>>(x, xT, delta, Bs, Cs, Alog, Dsv, Pg, Sg, y);
    kE<<<288, 256, 0, stream>>>(y, lnw, lnb, out);
}